// Round 17
// baseline (978.134 us; speedup 1.0000x reference)
//
#include <hip/hip_runtime.h>
#include <hip/hip_bf16.h>
#include <stdint.h>

#define N_EMBD    256
#define N_INPUTS  66
#define N_LEVELS  8
#define APL       4096
#define NPL       2048
#define LVL       6144
#define N_HID     1024

typedef __hip_bfloat16 bf16;
typedef __attribute__((ext_vector_type(8))) short short8;
typedef __attribute__((ext_vector_type(4))) float f32x4;

static __device__ __forceinline__ unsigned short f2b(float f) {
  bf16 h = __float2bfloat16(f);
  return *reinterpret_cast<unsigned short*>(&h);
}

// ---------------- input copy: rows 0..65 of node table ----------------
__global__ void k_copy_inputs(const float* __restrict__ in, float* __restrict__ out) {
  int r = blockIdx.x, t = threadIdx.x;  // 66 blocks x 64 threads
  ((float4*)(out + (size_t)r * 256))[t] = ((const float4*)(in + (size_t)r * 256))[t];
}

// ---------------- ALL weight transposes in ONE dispatch ----------------
__global__ void k_transpose_all(const float* __restrict__ W_in, const float* __restrict__ W_hid,
                                const float* __restrict__ W_out,
                                bf16* __restrict__ WtIn, bf16* __restrict__ WtHid,
                                bf16* __restrict__ WtOut) {
  __shared__ float t[32][33];
  int z = blockIdx.z;
  const float* in; bf16* out; int K, N;
  if (z == 0)      { in = W_in;  out = WtIn;  K = 512;  N = 1024; }
  else if (z <= 8) { in = W_hid + (size_t)(z - 1) * 1024 * 1024; out = WtHid + (size_t)(z - 1) * 1024 * 1024; K = 1024; N = 1024; }
  else             { in = W_out; out = WtOut; K = 1024; N = 256; }
  int n0 = blockIdx.x * 32, k0 = blockIdx.y * 32;
  if (n0 >= N || k0 >= K) return;
  int tx = threadIdx.x, ty = threadIdx.y;
  #pragma unroll
  for (int j = 0; j < 32; j += 8)
    t[ty + j][tx] = in[(size_t)(k0 + ty + j) * N + n0 + tx];
  __syncthreads();
  #pragma unroll
  for (int j = 0; j < 32; j += 8)
    out[(size_t)(n0 + ty + j) * K + k0 + tx] = __float2bfloat16(t[tx][ty + j]);
}

// ---------------- fused NOT + gather, 256-thread blocks (4 items each) ----------------
__global__ void k_not_gather(const int* __restrict__ xe, const int* __restrict__ ye,
                             float* __restrict__ node, bf16* __restrict__ H0, int s) {
  int t = threadIdx.x & 63;
  int b = blockIdx.x * 4 + (threadIdx.x >> 6);  // 0..6143
  if (b < NPL) {
    int dst = s + APL + b;
    int src = xe[dst];
    float4 v = ((const float4*)(node + (size_t)src * 256))[t];
    float4 o; o.x = -v.x; o.y = -v.y; o.z = -v.z; o.w = -v.w;
    ((float4*)(node + (size_t)dst * 256))[t] = o;
  } else {
    int r = b - NPL;
    int xa = xe[s + r], ya = ye[s + r];
    float4 vx = ((const float4*)(node + (size_t)xa * 256))[t];
    float4 vy = ((const float4*)(node + (size_t)ya * 256))[t];
    ushort4 ox, oy;
    ox.x = f2b(vx.x); ox.y = f2b(vx.y); ox.z = f2b(vx.z); ox.w = f2b(vx.w);
    oy.x = f2b(vy.x); oy.y = f2b(vy.y); oy.z = f2b(vy.z); oy.w = f2b(vy.w);
    bf16* hr = H0 + (size_t)r * 512;
    ((ushort4*)hr)[t] = ox;
    ((ushort4*)(hr + 256))[t] = oy;
  }
}

// ---------------- GEMM (R16 winner): 128x64 tile, 3-buffer 1-barrier/K-step ----------------
template<int BM, int BN, int NK, bool RELU, bool BF16OUT>
__global__ __launch_bounds__(256, 2)
void k_gemm(const bf16* __restrict__ A, const bf16* __restrict__ Bt,
            const float* __restrict__ bias, void* __restrict__ Cout,
            int M, int N, int K) {
  constexpr int MT = BM / 32;            // A-frags per wave (wave owns BM/2 rows)
  constexpr int NT = BN / 32;
  constexpr int AIT = BM / 32;           // A-load iters per STAGE
  constexpr int BIT = BN / 32;
  constexpr int ABYTES = BM * 128;       // BM rows x 64 bf16
  constexpr int BBYTES = BN * 128;
  constexpr int BUF = ABYTES + BBYTES;
  constexpr int LOADS = AIT + BIT;       // global_load_lds per thread per STAGE
  __shared__ __align__(16) char smem[3 * BUF];

  const int tid  = threadIdx.x;
  const int lane = tid & 63;
  const int w    = tid >> 6;
  const int wm   = w >> 1, wn = w & 1;
  const int m0 = blockIdx.x * BM;
  const int n0 = blockIdx.y * BN;

  const bf16* gA[AIT];
  const bf16* gB[BIT];
  #pragma unroll
  for (int it = 0; it < AIT; ++it) {
    int ci = it * 256 + tid;
    int r = ci >> 3, g = ci & 7, gs = g ^ (r & 7);
    gA[it] = A + (size_t)(m0 + r) * K + gs * 8;
  }
  #pragma unroll
  for (int it = 0; it < BIT; ++it) {
    int ci = it * 256 + tid;
    int r = ci >> 3, g = ci & 7, gs = g ^ (r & 7);
    gB[it] = Bt + (size_t)(n0 + r) * K + gs * 8;
  }

  int aoff[2][MT], boff[2][NT];
  #pragma unroll
  for (int kk = 0; kk < 2; ++kk) {
    #pragma unroll
    for (int mt = 0; mt < MT; ++mt) {
      int row = wm * (BM / 2) + mt * 16 + (lane & 15);
      int g = kk * 4 + (lane >> 4);
      aoff[kk][mt] = row * 128 + ((g ^ (row & 7)) * 16);
    }
    #pragma unroll
    for (int nt = 0; nt < NT; ++nt) {
      int row = wn * (BN / 2) + nt * 16 + (lane & 15);
      int g = kk * 4 + (lane >> 4);
      boff[kk][nt] = ABYTES + row * 128 + ((g ^ (row & 7)) * 16);
    }
  }

  f32x4 acc[MT][NT] = {};

  auto STAGE = [&](char* base) {
    char* sA = base;
    char* sB = base + ABYTES;
    #pragma unroll
    for (int it = 0; it < AIT; ++it) {
      __builtin_amdgcn_global_load_lds((const __attribute__((address_space(1))) void*)gA[it],
                                       (__attribute__((address_space(3))) void*)(sA + (it * 256 + w * 64) * 16),
                                       16, 0, 0);
      gA[it] += 64;
    }
    #pragma unroll
    for (int it = 0; it < BIT; ++it) {
      __builtin_amdgcn_global_load_lds((const __attribute__((address_space(1))) void*)gB[it],
                                       (__attribute__((address_space(3))) void*)(sB + (it * 256 + w * 64) * 16),
                                       16, 0, 0);
      gB[it] += 64;
    }
  };

  auto COMPUTE = [&](char* base) {
    #pragma unroll
    for (int kk = 0; kk < 2; ++kk) {
      short8 af[MT], bfr[NT];
      #pragma unroll
      for (int mt = 0; mt < MT; ++mt)
        af[mt] = *(const short8*)(base + aoff[kk][mt]);
      #pragma unroll
      for (int nt = 0; nt < NT; ++nt)
        bfr[nt] = *(const short8*)(base + boff[kk][nt]);
      #pragma unroll
      for (int mt = 0; mt < MT; ++mt)
        #pragma unroll
        for (int nt = 0; nt < NT; ++nt)
          acc[mt][nt] = __builtin_amdgcn_mfma_f32_16x16x32_bf16(af[mt], bfr[nt], acc[mt][nt], 0, 0, 0);
    }
  };

  STAGE(smem);
  STAGE(smem + BUF);

  #pragma unroll
  for (int t = 0; t < NK; ++t) {
    if (t < NK - 1) {
      if constexpr (LOADS == 6)      asm volatile("s_waitcnt vmcnt(6)" ::: "memory");
      else if constexpr (LOADS == 4) asm volatile("s_waitcnt vmcnt(4)" ::: "memory");
      else                           asm volatile("s_waitcnt vmcnt(0)" ::: "memory");
    } else {
      asm volatile("s_waitcnt vmcnt(0)" ::: "memory");
    }
    __builtin_amdgcn_s_barrier();           // batch t landed (all waves); buf (t-1)%3 free
    if (t + 2 < NK) STAGE(smem + ((t + 2) % 3) * BUF);  // batch t+2 into buf (t-1)%3
    COMPUTE(smem + (t % 3) * BUF);
  }

  #pragma unroll
  for (int nt = 0; nt < NT; ++nt) {
    int col = n0 + wn * (BN / 2) + nt * 16 + (lane & 15);
    float bv = bias[col];
    #pragma unroll
    for (int mt = 0; mt < MT; ++mt) {
      int rbase = m0 + wm * (BM / 2) + mt * 16 + (lane >> 4) * 4;
      #pragma unroll
      for (int r = 0; r < 4; ++r) {
        float v = acc[mt][nt][r] + bv;
        if (RELU) v = fmaxf(v, 0.f);
        if (BF16OUT)
          ((unsigned short*)Cout)[(size_t)(rbase + r) * N + col] = f2b(v);
        else
          ((float*)Cout)[(size_t)(rbase + r) * N + col] = v;
      }
    }
  }
}

// ---------------- FUSED out-GEMM + LayerNorm ----------------
// Block = 64 rows x ALL 256 cols (grid 64). 4 waves, each 64x64 quadrant (MT=NT=4).
// Same R16 3-buffer 1-barrier pipeline, LOADS=10 (A:2 + B:8). After K-loop:
// C(+bias, f32) -> LDS tile (aliases staging bufs, barrier-guarded), then per-wave
// LN over 16 rows with the EXACT k_ln reduce order -> bit-identical output.
__global__ __launch_bounds__(256, 1)
void k_gemm_out_ln(const bf16* __restrict__ A, const bf16* __restrict__ Bt,
                   const float* __restrict__ bias, const float* __restrict__ g,
                   const float* __restrict__ b, float* __restrict__ node,
                   int s, int K) {
  constexpr int NK = 16;
  constexpr int MT = 4, NT = 4, AIT = 2, BIT = 8;
  constexpr int ABYTES = 64 * 128;       // 8 KB (64 rows x 64 bf16)
  constexpr int BBYTES = 256 * 128;      // 32 KB (256 Bt-rows x 64 bf16)
  constexpr int BUF = ABYTES + BBYTES;   // 40 KB
  __shared__ __align__(16) char smem[3 * BUF];  // 120 KB; first 64 KB reused as C-tile
  float* cls = (float*)smem;             // C-tile 64 x 256 f32

  const int tid  = threadIdx.x;
  const int lane = tid & 63;
  const int w    = tid >> 6;             // wave = col quadrant
  const int m0 = blockIdx.x * 64;

  const bf16* gA[AIT];
  const bf16* gB[BIT];
  #pragma unroll
  for (int it = 0; it < AIT; ++it) {
    int ci = it * 256 + tid;             // 0..511 -> rows 0..63
    int r = ci >> 3, gg = ci & 7, gs = gg ^ (r & 7);
    gA[it] = A + (size_t)(m0 + r) * K + gs * 8;
  }
  #pragma unroll
  for (int it = 0; it < BIT; ++it) {
    int ci = it * 256 + tid;             // 0..2047 -> Bt rows 0..255
    int r = ci >> 3, gg = ci & 7, gs = gg ^ (r & 7);
    gB[it] = Bt + (size_t)r * K + gs * 8;
  }

  int aoff[2][MT], boff[2][NT];
  #pragma unroll
  for (int kk = 0; kk < 2; ++kk) {
    #pragma unroll
    for (int mt = 0; mt < MT; ++mt) {
      int row = mt * 16 + (lane & 15);   // all waves share the 64 rows
      int gg = kk * 4 + (lane >> 4);
      aoff[kk][mt] = row * 128 + ((gg ^ (row & 7)) * 16);
    }
    #pragma unroll
    for (int nt = 0; nt < NT; ++nt) {
      int row = w * 64 + nt * 16 + (lane & 15);  // wave's col quadrant
      int gg = kk * 4 + (lane >> 4);
      boff[kk][nt] = ABYTES + row * 128 + ((gg ^ (row & 7)) * 16);
    }
  }

  f32x4 acc[MT][NT] = {};

  auto STAGE = [&](char* base) {
    char* sA = base;
    char* sB = base + ABYTES;
    #pragma unroll
    for (int it = 0; it < AIT; ++it) {
      __builtin_amdgcn_global_load_lds((const __attribute__((address_space(1))) void*)gA[it],
                                       (__attribute__((address_space(3))) void*)(sA + (it * 256 + w * 64) * 16),
                                       16, 0, 0);
      gA[it] += 64;
    }
    #pragma unroll
    for (int it = 0; it < BIT; ++it) {
      __builtin_amdgcn_global_load_lds((const __attribute__((address_space(1))) void*)gB[it],
                                       (__attribute__((address_space(3))) void*)(sB + (it * 256 + w * 64) * 16),
                                       16, 0, 0);
      gB[it] += 64;
    }
  };

  auto COMPUTE = [&](char* base) {
    #pragma unroll
    for (int kk = 0; kk < 2; ++kk) {
      short8 af[MT], bfr[NT];
      #pragma unroll
      for (int mt = 0; mt < MT; ++mt)
        af[mt] = *(const short8*)(base + aoff[kk][mt]);
      #pragma unroll
      for (int nt = 0; nt < NT; ++nt)
        bfr[nt] = *(const short8*)(base + boff[kk][nt]);
      #pragma unroll
      for (int mt = 0; mt < MT; ++mt)
        #pragma unroll
        for (int nt = 0; nt < NT; ++nt)
          acc[mt][nt] = __builtin_amdgcn_mfma_f32_16x16x32_bf16(af[mt], bfr[nt], acc[mt][nt], 0, 0, 0);
    }
  };

  STAGE(smem);
  STAGE(smem + BUF);

  #pragma unroll
  for (int t = 0; t < NK; ++t) {
    if (t < NK - 1) asm volatile("s_waitcnt vmcnt(10)" ::: "memory");
    else            asm volatile("s_waitcnt vmcnt(0)" ::: "memory");
    __builtin_amdgcn_s_barrier();
    if (t + 2 < NK) STAGE(smem + ((t + 2) % 3) * BUF);
    COMPUTE(smem + (t % 3) * BUF);
  }

  __syncthreads();  // all waves done with staging LDS before C-tile overwrite

  // C(+bias) -> LDS f32 tile
  #pragma unroll
  for (int nt = 0; nt < NT; ++nt) {
    int col = w * 64 + nt * 16 + (lane & 15);
    float bv = bias[col];
    #pragma unroll
    for (int mt = 0; mt < MT; ++mt) {
      int rbase = mt * 16 + (lane >> 4) * 4;
      #pragma unroll
      for (int r = 0; r < 4; ++r)
        cls[(size_t)(rbase + r) * 256 + col] = acc[mt][nt][r] + bv;
    }
  }
  __syncthreads();

  // LayerNorm: wave w handles rows [w*16, w*16+16), k_ln-identical reduce order
  float4 gv = ((const float4*)g)[lane];
  float4 bv4 = ((const float4*)b)[lane];
  #pragma unroll
  for (int rr = 0; rr < 16; ++rr) {
    int row = w * 16 + rr;
    float4 x = ((const float4*)(cls + (size_t)row * 256))[lane];
    float sm = x.x + x.y + x.z + x.w;
    float sq = x.x * x.x + x.y * x.y + x.z * x.z + x.w * x.w;
    #pragma unroll
    for (int o = 1; o < 64; o <<= 1) { sm += __shfl_xor(sm, o); sq += __shfl_xor(sq, o); }
    float mu  = sm * (1.f / 256.f);
    float var = sq * (1.f / 256.f) - mu * mu;
    float rs  = rsqrtf(var + 1e-5f);
    float4 o4;
    o4.x = (x.x - mu) * rs * gv.x + bv4.x;
    o4.y = (x.y - mu) * rs * gv.y + bv4.y;
    o4.z = (x.z - mu) * rs * gv.z + bv4.z;
    o4.w = (x.w - mu) * rs * gv.w + bv4.w;
    ((float4*)(node + (size_t)(s + m0 + row) * 256))[lane] = o4;
  }
}

extern "C" void kernel_launch(void* const* d_in, const int* in_sizes, int n_in,
                              void* d_out, int out_size, void* d_ws, size_t ws_size,
                              hipStream_t stream) {
  const int*   x_edges    = (const int*)d_in[1];
  const int*   y_edges    = (const int*)d_in[2];
  const float* input_embd = (const float*)d_in[3];
  const float* W_in       = (const float*)d_in[4];
  const float* b_in       = (const float*)d_in[5];
  const float* W_hid      = (const float*)d_in[6];
  const float* b_hid      = (const float*)d_in[7];
  const float* W_out      = (const float*)d_in[8];
  const float* b_out      = (const float*)d_in[9];
  const float* ln_g       = (const float*)d_in[10];
  const float* ln_b       = (const float*)d_in[11];
  float* node = (float*)d_out;

  char* ws = (char*)d_ws;
  bf16* WtIn  = (bf16*)(ws);                                   // 1024x512
  bf16* WtHid = (bf16*)(ws + (size_t)1048576);                 // 8x1024x1024
  bf16* WtOut = (bf16*)(ws + (size_t)17825792);                // 256x1024
  bf16* H0    = (bf16*)(ws + (size_t)18350080);                // 4096x512
  bf16* HA    = (bf16*)(ws + (size_t)22544384);                // 4096x1024
  bf16* HB    = (bf16*)(ws + (size_t)30932992);                // 4096x1024

  // node rows 0..65 = input embeddings
  k_copy_inputs<<<dim3(66), dim3(64), 0, stream>>>(input_embd, node);

  // all weight transposes in one dispatch
  k_transpose_all<<<dim3(32, 32, 10), dim3(32, 8), 0, stream>>>(W_in, W_hid, W_out, WtIn, WtHid, WtOut);

  for (int l = 0; l < N_LEVELS; ++l) {
    int s = N_INPUTS + l * LVL;
    k_not_gather<<<dim3((NPL + APL) / 4), dim3(256), 0, stream>>>(x_edges, y_edges, node, H0, s);

    // MLP: 128x64 tiles -> 512 blocks (2/CU), 3-buffer 1-barrier/K-step pipeline
    k_gemm<128, 64, 8, true, true><<<dim3(32, 16), dim3(256), 0, stream>>>(H0, WtIn, b_in, HA, 4096, 1024, 512);
    const bf16* src = HA; bf16* dst = HB;
    for (int i = 0; i < 8; ++i) {
      k_gemm<128, 64, 16, true, true><<<dim3(32, 16), dim3(256), 0, stream>>>(
          src, WtHid + (size_t)i * 1024 * 1024, b_hid + i * 1024, dst, 4096, 1024, 1024);
      const bf16* tmp = src; src = dst; dst = (bf16*)tmp;
    }
    // src == HA here; fused out-GEMM + LayerNorm straight into node
    k_gemm_out_ln<<<dim3(64), dim3(256), 0, stream>>>(src, WtOut, b_out, ln_g, ln_b, node, s, 1024);
  }
}

// Round 18
// 942.353 us; speedup vs baseline: 1.0380x; 1.0380x over previous
//
#include <hip/hip_runtime.h>
#include <hip/hip_bf16.h>
#include <stdint.h>

#define N_EMBD    256
#define N_INPUTS  66
#define N_LEVELS  8
#define APL       4096
#define NPL       2048
#define LVL       6144
#define N_HID     1024

typedef __hip_bfloat16 bf16;
typedef __attribute__((ext_vector_type(8))) short short8;
typedef __attribute__((ext_vector_type(4))) float f32x4;

static __device__ __forceinline__ unsigned short f2b(float f) {
  bf16 h = __float2bfloat16(f);
  return *reinterpret_cast<unsigned short*>(&h);
}

// ---------------- input copy: rows 0..65 of node table ----------------
__global__ void k_copy_inputs(const float* __restrict__ in, float* __restrict__ out) {
  int r = blockIdx.x, t = threadIdx.x;  // 66 blocks x 64 threads
  ((float4*)(out + (size_t)r * 256))[t] = ((const float4*)(in + (size_t)r * 256))[t];
}

// ---------------- ALL weight transposes in ONE dispatch ----------------
__global__ void k_transpose_all(const float* __restrict__ W_in, const float* __restrict__ W_hid,
                                const float* __restrict__ W_out,
                                bf16* __restrict__ WtIn, bf16* __restrict__ WtHid,
                                bf16* __restrict__ WtOut) {
  __shared__ float t[32][33];
  int z = blockIdx.z;
  const float* in; bf16* out; int K, N;
  if (z == 0)      { in = W_in;  out = WtIn;  K = 512;  N = 1024; }
  else if (z <= 8) { in = W_hid + (size_t)(z - 1) * 1024 * 1024; out = WtHid + (size_t)(z - 1) * 1024 * 1024; K = 1024; N = 1024; }
  else             { in = W_out; out = WtOut; K = 1024; N = 256; }
  int n0 = blockIdx.x * 32, k0 = blockIdx.y * 32;
  if (n0 >= N || k0 >= K) return;
  int tx = threadIdx.x, ty = threadIdx.y;
  #pragma unroll
  for (int j = 0; j < 32; j += 8)
    t[ty + j][tx] = in[(size_t)(k0 + ty + j) * N + n0 + tx];
  __syncthreads();
  #pragma unroll
  for (int j = 0; j < 32; j += 8)
    out[(size_t)(n0 + ty + j) * K + k0 + tx] = __float2bfloat16(t[tx][ty + j]);
}

// ---------------- fused NOT + gather, 256-thread blocks (4 items each) ----------------
__global__ void k_not_gather(const int* __restrict__ xe, const int* __restrict__ ye,
                             float* __restrict__ node, bf16* __restrict__ H0, int s) {
  int t = threadIdx.x & 63;
  int b = blockIdx.x * 4 + (threadIdx.x >> 6);  // 0..6143
  if (b < NPL) {
    int dst = s + APL + b;
    int src = xe[dst];
    float4 v = ((const float4*)(node + (size_t)src * 256))[t];
    float4 o; o.x = -v.x; o.y = -v.y; o.z = -v.z; o.w = -v.w;
    ((float4*)(node + (size_t)dst * 256))[t] = o;
  } else {
    int r = b - NPL;
    int xa = xe[s + r], ya = ye[s + r];
    float4 vx = ((const float4*)(node + (size_t)xa * 256))[t];
    float4 vy = ((const float4*)(node + (size_t)ya * 256))[t];
    ushort4 ox, oy;
    ox.x = f2b(vx.x); ox.y = f2b(vx.y); ox.z = f2b(vx.z); ox.w = f2b(vx.w);
    oy.x = f2b(vy.x); oy.y = f2b(vy.y); oy.z = f2b(vy.z); oy.w = f2b(vy.w);
    bf16* hr = H0 + (size_t)r * 512;
    ((ushort4*)hr)[t] = ox;
    ((ushort4*)(hr + 256))[t] = oy;
  }
}

// ---------------- GEMM (R16 winner): 128x64 tile, 3-buffer 1-barrier/K-step ----------------
// 4 waves (2x2), wave (BM/2)x(BN/2), mfma 16x16x32, 2 blocks/CU, counted vmcnt.
// Stage of batch t+2 goes into buffer (t+2)%3 == (t-1)%3, whose readers finished
// before their step-t entry barrier -> race-safe with ONE barrier per K-step.
// Each load batch gets two compute phases of latency cover.
// global_load_lds width 16, XOR-swizzle on global SOURCE + on ds_read (rule #21).
template<int BM, int BN, int NK, bool RELU, bool BF16OUT>
__global__ __launch_bounds__(256, 2)
void k_gemm(const bf16* __restrict__ A, const bf16* __restrict__ Bt,
            const float* __restrict__ bias, void* __restrict__ Cout,
            int M, int N, int K) {
  constexpr int MT = BM / 32;            // A-frags per wave (wave owns BM/2 rows)
  constexpr int NT = BN / 32;
  constexpr int AIT = BM / 32;           // A-load iters per STAGE
  constexpr int BIT = BN / 32;
  constexpr int ABYTES = BM * 128;       // BM rows x 64 bf16
  constexpr int BBYTES = BN * 128;
  constexpr int BUF = ABYTES + BBYTES;
  constexpr int LOADS = AIT + BIT;       // global_load_lds per thread per STAGE
  __shared__ __align__(16) char smem[3 * BUF];

  const int tid  = threadIdx.x;
  const int lane = tid & 63;
  const int w    = tid >> 6;
  const int wm   = w >> 1, wn = w & 1;
  const int m0 = blockIdx.x * BM;
  const int n0 = blockIdx.y * BN;

  const bf16* gA[AIT];
  const bf16* gB[BIT];
  #pragma unroll
  for (int it = 0; it < AIT; ++it) {
    int ci = it * 256 + tid;
    int r = ci >> 3, g = ci & 7, gs = g ^ (r & 7);
    gA[it] = A + (size_t)(m0 + r) * K + gs * 8;
  }
  #pragma unroll
  for (int it = 0; it < BIT; ++it) {
    int ci = it * 256 + tid;
    int r = ci >> 3, g = ci & 7, gs = g ^ (r & 7);
    gB[it] = Bt + (size_t)(n0 + r) * K + gs * 8;
  }

  int aoff[2][MT], boff[2][NT];
  #pragma unroll
  for (int kk = 0; kk < 2; ++kk) {
    #pragma unroll
    for (int mt = 0; mt < MT; ++mt) {
      int row = wm * (BM / 2) + mt * 16 + (lane & 15);
      int g = kk * 4 + (lane >> 4);
      aoff[kk][mt] = row * 128 + ((g ^ (row & 7)) * 16);
    }
    #pragma unroll
    for (int nt = 0; nt < NT; ++nt) {
      int row = wn * (BN / 2) + nt * 16 + (lane & 15);
      int g = kk * 4 + (lane >> 4);
      boff[kk][nt] = ABYTES + row * 128 + ((g ^ (row & 7)) * 16);
    }
  }

  f32x4 acc[MT][NT] = {};

  auto STAGE = [&](char* base) {
    char* sA = base;
    char* sB = base + ABYTES;
    #pragma unroll
    for (int it = 0; it < AIT; ++it) {
      __builtin_amdgcn_global_load_lds((const __attribute__((address_space(1))) void*)gA[it],
                                       (__attribute__((address_space(3))) void*)(sA + (it * 256 + w * 64) * 16),
                                       16, 0, 0);
      gA[it] += 64;
    }
    #pragma unroll
    for (int it = 0; it < BIT; ++it) {
      __builtin_amdgcn_global_load_lds((const __attribute__((address_space(1))) void*)gB[it],
                                       (__attribute__((address_space(3))) void*)(sB + (it * 256 + w * 64) * 16),
                                       16, 0, 0);
      gB[it] += 64;
    }
  };

  auto COMPUTE = [&](char* base) {
    #pragma unroll
    for (int kk = 0; kk < 2; ++kk) {
      short8 af[MT], bfr[NT];
      #pragma unroll
      for (int mt = 0; mt < MT; ++mt)
        af[mt] = *(const short8*)(base + aoff[kk][mt]);
      #pragma unroll
      for (int nt = 0; nt < NT; ++nt)
        bfr[nt] = *(const short8*)(base + boff[kk][nt]);
      #pragma unroll
      for (int mt = 0; mt < MT; ++mt)
        #pragma unroll
        for (int nt = 0; nt < NT; ++nt)
          acc[mt][nt] = __builtin_amdgcn_mfma_f32_16x16x32_bf16(af[mt], bfr[nt], acc[mt][nt], 0, 0, 0);
    }
  };

  STAGE(smem);
  STAGE(smem + BUF);

  #pragma unroll
  for (int t = 0; t < NK; ++t) {
    if (t < NK - 1) {
      if constexpr (LOADS == 6)      asm volatile("s_waitcnt vmcnt(6)" ::: "memory");
      else if constexpr (LOADS == 4) asm volatile("s_waitcnt vmcnt(4)" ::: "memory");
      else                           asm volatile("s_waitcnt vmcnt(0)" ::: "memory");
    } else {
      asm volatile("s_waitcnt vmcnt(0)" ::: "memory");
    }
    __builtin_amdgcn_s_barrier();           // batch t landed (all waves); buf (t-1)%3 free
    if (t + 2 < NK) STAGE(smem + ((t + 2) % 3) * BUF);  // batch t+2 into buf (t-1)%3
    COMPUTE(smem + (t % 3) * BUF);
  }

  #pragma unroll
  for (int nt = 0; nt < NT; ++nt) {
    int col = n0 + wn * (BN / 2) + nt * 16 + (lane & 15);
    float bv = bias[col];
    #pragma unroll
    for (int mt = 0; mt < MT; ++mt) {
      int rbase = m0 + wm * (BM / 2) + mt * 16 + (lane >> 4) * 4;
      #pragma unroll
      for (int r = 0; r < 4; ++r) {
        float v = acc[mt][nt][r] + bv;
        if (RELU) v = fmaxf(v, 0.f);
        if (BF16OUT)
          ((unsigned short*)Cout)[(size_t)(rbase + r) * N + col] = f2b(v);
        else
          ((float*)Cout)[(size_t)(rbase + r) * N + col] = v;
      }
    }
  }
}

// ---------------- LayerNorm, 256-thread blocks (4 rows each) ----------------
__global__ void k_ln(const float* __restrict__ X, const float* __restrict__ g,
                     const float* __restrict__ b, float* __restrict__ node, int s) {
  int t = threadIdx.x & 63;
  int r = blockIdx.x * 4 + (threadIdx.x >> 6);  // 0..4095
  float4 x = ((const float4*)(X + (size_t)r * 256))[t];
  float sm = x.x + x.y + x.z + x.w;
  float sq = x.x * x.x + x.y * x.y + x.z * x.z + x.w * x.w;
  #pragma unroll
  for (int o = 1; o < 64; o <<= 1) { sm += __shfl_xor(sm, o); sq += __shfl_xor(sq, o); }
  float mu  = sm * (1.f / 256.f);
  float var = sq * (1.f / 256.f) - mu * mu;
  float rs  = rsqrtf(var + 1e-5f);
  float4 gv = ((const float4*)g)[t], bv = ((const float4*)b)[t];
  float4 o4;
  o4.x = (x.x - mu) * rs * gv.x + bv.x;
  o4.y = (x.y - mu) * rs * gv.y + bv.y;
  o4.z = (x.z - mu) * rs * gv.z + bv.z;
  o4.w = (x.w - mu) * rs * gv.w + bv.w;
  ((float4*)(node + (size_t)(s + r) * 256))[t] = o4;
}

extern "C" void kernel_launch(void* const* d_in, const int* in_sizes, int n_in,
                              void* d_out, int out_size, void* d_ws, size_t ws_size,
                              hipStream_t stream) {
  const int*   x_edges    = (const int*)d_in[1];
  const int*   y_edges    = (const int*)d_in[2];
  const float* input_embd = (const float*)d_in[3];
  const float* W_in       = (const float*)d_in[4];
  const float* b_in       = (const float*)d_in[5];
  const float* W_hid      = (const float*)d_in[6];
  const float* b_hid      = (const float*)d_in[7];
  const float* W_out      = (const float*)d_in[8];
  const float* b_out      = (const float*)d_in[9];
  const float* ln_g       = (const float*)d_in[10];
  const float* ln_b       = (const float*)d_in[11];
  float* node = (float*)d_out;

  char* ws = (char*)d_ws;
  bf16* WtIn  = (bf16*)(ws);                                   // 1024x512
  bf16* WtHid = (bf16*)(ws + (size_t)1048576);                 // 8x1024x1024
  bf16* WtOut = (bf16*)(ws + (size_t)17825792);                // 256x1024
  bf16* H0    = (bf16*)(ws + (size_t)18350080);                // 4096x512
  bf16* HA    = (bf16*)(ws + (size_t)22544384);                // 4096x1024
  bf16* HB    = (bf16*)(ws + (size_t)30932992);                // 4096x1024
  float* OutF = (float*)HB;                                    // reuse (4096x256 f32)

  // node rows 0..65 = input embeddings
  k_copy_inputs<<<dim3(66), dim3(64), 0, stream>>>(input_embd, node);

  // all weight transposes in one dispatch
  k_transpose_all<<<dim3(32, 32, 10), dim3(32, 8), 0, stream>>>(W_in, W_hid, W_out, WtIn, WtHid, WtOut);

  for (int l = 0; l < N_LEVELS; ++l) {
    int s = N_INPUTS + l * LVL;
    k_not_gather<<<dim3((NPL + APL) / 4), dim3(256), 0, stream>>>(x_edges, y_edges, node, H0, s);

    // MLP: 128x64 tiles -> 512 blocks (2/CU), 3-buffer 1-barrier/K-step pipeline
    k_gemm<128, 64, 8, true, true><<<dim3(32, 16), dim3(256), 0, stream>>>(H0, WtIn, b_in, HA, 4096, 1024, 512);
    const bf16* src = HA; bf16* dst = HB;
    for (int i = 0; i < 8; ++i) {
      k_gemm<128, 64, 16, true, true><<<dim3(32, 16), dim3(256), 0, stream>>>(
          src, WtHid + (size_t)i * 1024 * 1024, b_hid + i * 1024, dst, 4096, 1024, 1024);
      const bf16* tmp = src; src = dst; dst = (bf16*)tmp;
    }
    // src == HA here; fp32 MLP output into OutF (= HB space, no longer needed)
    k_gemm<64, 64, 16, false, false><<<dim3(64, 4), dim3(256), 0, stream>>>(src, WtOut, b_out, OutF, 4096, 256, 1024);

    k_ln<<<dim3(APL / 4), dim3(256), 0, stream>>>(OutF, ln_g, ln_b, node, s);
  }
}